// Round 2
// baseline (245.843 us; speedup 1.0000x reference)
//
#include <hip/hip_runtime.h>
#include <hip/hip_bf16.h>

// Problem constants (from reference)
#define BB 4      // batch
#define SS 1023   // source length = 2T-1
#define TT 512    // window length / number of query positions
#define CC 1024   // embed dim
#define DD 64     // head size

// ---------------------------------------------------------------------------
// Kernel 1: projections k = x@Wk, v = x@Wv, q = x[:, -T:, :]@Wq  (fp32)
// one block per (b, s) row; 192 threads: wave0 -> k, wave1 -> v, wave2 -> q
// ---------------------------------------------------------------------------
__global__ __launch_bounds__(192) void proj_kernel(
    const float* __restrict__ x,
    const float* __restrict__ Wk,
    const float* __restrict__ Wv,
    const float* __restrict__ Wq,
    float* __restrict__ kbuf,   // [B*S*D]
    float* __restrict__ vbuf,   // [B*S*D]
    float* __restrict__ qbuf)   // [B*T*D]
{
    __shared__ float xs[CC];
    const int bs = blockIdx.x;          // 0 .. B*S-1
    const int b  = bs / SS;
    const int s  = bs % SS;

    const float* xrow = x + (size_t)bs * CC;
    for (int i = threadIdx.x; i < CC; i += 192)
        xs[i] = xrow[i];
    __syncthreads();

    const int d     = threadIdx.x & 63;
    const int which = threadIdx.x >> 6;          // 0=k, 1=v, 2=q
    if (which == 2 && s < TT - 1) return;        // q only for last T rows

    const float* W = (which == 0) ? Wk : (which == 1) ? Wv : Wq;

    float acc = 0.f;
#pragma unroll 8
    for (int c = 0; c < CC; ++c)
        acc += xs[c] * W[c * DD + d];

    if (which == 0)      kbuf[(size_t)bs * DD + d] = acc;
    else if (which == 1) vbuf[(size_t)bs * DD + d] = acc;
    else                 qbuf[((size_t)b * TT + (s - (TT - 1))) * DD + d] = acc;
}

// ---------------------------------------------------------------------------
// Kernel 2: attention per (b, w):
//   wei[t] = q[b,w,:] . (k[b,w+t,:] + bias[:,t]),  softmax over t,
//   out[b,w,:] = sum_t wei[t] * v[b,w+t,:]
// 256 threads = 4 waves. Phase 1: thread handles t = tid, tid+256.
// Phase 2: wave j accumulates t in [128j, 128j+128), lane d = tid&63.
// ---------------------------------------------------------------------------
__global__ __launch_bounds__(256) void attn_kernel(
    const float* __restrict__ kbuf,
    const float* __restrict__ vbuf,
    const float* __restrict__ qbuf,
    const float* __restrict__ bias,   // [D, T] : bias[d*T + t]
    float* __restrict__ out)          // [B*T*D]
{
    __shared__ float qs[DD];
    __shared__ float wei[TT];
    __shared__ float red[8];
    __shared__ float partial[4][DD];

    const int bw  = blockIdx.x;        // 0 .. B*T-1
    const int b   = bw >> 9;           // / 512
    const int w   = bw & (TT - 1);     // % 512
    const int tid = threadIdx.x;
    const int wave = tid >> 6;
    const int lane = tid & 63;

    if (tid < DD) qs[tid] = qbuf[(size_t)bw * DD + tid];
    __syncthreads();

    // ---- phase 1: logits ----
    float l[2];
#pragma unroll
    for (int j = 0; j < 2; ++j) {
        const int t = tid + j * 256;
        const float* krow = kbuf + ((size_t)(b * SS + w + t)) * DD;
        float acc = 0.f;
#pragma unroll
        for (int dd = 0; dd < DD; ++dd)
            acc += qs[dd] * (krow[dd] + bias[dd * TT + t]);
        l[j] = acc;
    }

    // ---- block max ----
    float m = fmaxf(l[0], l[1]);
#pragma unroll
    for (int off = 32; off; off >>= 1)
        m = fmaxf(m, __shfl_down(m, off, 64));
    if (lane == 0) red[wave] = m;
    __syncthreads();
    m = fmaxf(fmaxf(red[0], red[1]), fmaxf(red[2], red[3]));

    // ---- exp + block sum ----
    const float e0 = __expf(l[0] - m);
    const float e1 = __expf(l[1] - m);
    wei[tid]       = e0;
    wei[tid + 256] = e1;
    float ssum = e0 + e1;
#pragma unroll
    for (int off = 32; off; off >>= 1)
        ssum += __shfl_down(ssum, off, 64);
    if (lane == 0) red[4 + wave] = ssum;
    __syncthreads();
    const float inv = 1.f / (red[4] + red[5] + red[6] + red[7]);

    // ---- phase 2: out[d] = sum_t wei[t] * v[b, w+t, d] ----
    {
        const int d = lane;
        float acc = 0.f;
        const float* vbase = vbuf + ((size_t)(b * SS + w)) * DD + d;
        const int t0 = wave * 128;
#pragma unroll 4
        for (int t = t0; t < t0 + 128; ++t)
            acc += wei[t] * vbase[(size_t)t * DD];
        partial[wave][d] = acc;
    }
    __syncthreads();

    if (tid < DD) {
        const float o = (partial[0][tid] + partial[1][tid] +
                         partial[2][tid] + partial[3][tid]) * inv;
        out[(size_t)bw * DD + tid] = o;
    }
}

// ---------------------------------------------------------------------------
extern "C" void kernel_launch(void* const* d_in, const int* in_sizes, int n_in,
                              void* d_out, int out_size, void* d_ws, size_t ws_size,
                              hipStream_t stream) {
    const float* x    = (const float*)d_in[0];
    const float* Wk   = (const float*)d_in[1];
    const float* Wv   = (const float*)d_in[2];
    const float* Wq   = (const float*)d_in[3];
    const float* bias = (const float*)d_in[4];
    float* out = (float*)d_out;

    float* kbuf = (float*)d_ws;                       // B*S*D floats
    float* vbuf = kbuf + (size_t)BB * SS * DD;        // B*S*D floats
    float* qbuf = vbuf + (size_t)BB * SS * DD;        // B*T*D floats

    proj_kernel<<<BB * SS, 192, 0, stream>>>(x, Wk, Wv, Wq, kbuf, vbuf, qbuf);
    attn_kernel<<<BB * TT, 256, 0, stream>>>(kbuf, vbuf, qbuf, bias, out);
}

// Round 3
// 182.975 us; speedup vs baseline: 1.3436x; 1.3436x over previous
//
#include <hip/hip_runtime.h>
#include <hip/hip_bf16.h>

#define BB 4      // batch
#define SS 1023   // source length = 2T-1
#define TT 512    // window length
#define CC 1024   // embed dim
#define DD 64     // head size
#define NROW (BB*SS)   // 4092
#define RR 8      // rows per proj block

// ---------------------------------------------------------------------------
// Kernel 1: projections. Each block computes RR=8 rows x {k,v,q}.
// 256 threads = 4 waves; wave wv handles c in [wv*256, wv*256+256).
// Thread holds acc[3][8] (proj x row). x values are wave-uniform (scalar
// path); W loads coalesced (lane = d). LDS reduce across the 4 waves.
// k is stored TRANSPOSED: kT[d][bs] so attn phase-1 is coalesced in t.
// ---------------------------------------------------------------------------
__global__ __launch_bounds__(256) void proj_kernel(
    const float* __restrict__ x,
    const float* __restrict__ Wk,
    const float* __restrict__ Wv,
    const float* __restrict__ Wq,
    float* __restrict__ kT,     // [DD][NROW]
    float* __restrict__ vbuf,   // [NROW][DD]
    float* __restrict__ qbuf)   // [BB*TT][DD]
{
    __shared__ float red[4][DD * RR];   // 8 KB

    const int bs0 = blockIdx.x * RR;
    const int tid = threadIdx.x;
    const int d   = tid & 63;
    const int wv  = tid >> 6;

    const int s0 = bs0 % SS;
    const bool needq = (s0 + RR - 1) >= (TT - 1);   // any row needs q?
    const int nr = (NROW - bs0 < RR) ? (NROW - bs0) : RR;

    // clamped x row pointers (OOB rows read row 4091, discarded at store)
    const float* xr[RR];
#pragma unroll
    for (int r = 0; r < RR; ++r) {
        int bs = bs0 + r; if (bs > NROW - 1) bs = NROW - 1;
        xr[r] = x + (size_t)bs * CC;
    }

    float acc[3][RR];
#pragma unroll
    for (int p = 0; p < 3; ++p)
#pragma unroll
        for (int r = 0; r < RR; ++r) acc[p][r] = 0.f;

    const float* wkp = Wk + d;
    const float* wvp = Wv + d;
    const float* wqp = Wq + d;
    const int c0 = wv * 256;

    for (int cc = 0; cc < 256; ++cc) {
        const int c = c0 + cc;
        const float wk = wkp[c * DD];
        const float wl = wvp[c * DD];
#pragma unroll
        for (int r = 0; r < RR; ++r) {
            const float xv = xr[r][c];
            acc[0][r] = fmaf(xv, wk, acc[0][r]);
            acc[1][r] = fmaf(xv, wl, acc[1][r]);
        }
        if (needq) {
            const float wq = wqp[c * DD];
#pragma unroll
            for (int r = 0; r < RR; ++r)
                acc[2][r] = fmaf(xr[r][c], wq, acc[2][r]);
        }
    }

    // ---- reduce + store, one projection at a time ----
    for (int p = 0; p < 3; ++p) {
        if (p == 2 && !needq) break;
        // write partials: p==0 uses [d*RR+r] layout (for kT stores),
        // p>0 uses [r*DD+d] layout (for row-major stores)
        if (p == 0) {
#pragma unroll
            for (int r = 0; r < RR; ++r) red[wv][d * RR + r] = acc[0][r];
        } else {
#pragma unroll
            for (int r = 0; r < RR; ++r) red[wv][r * DD + d] = acc[p][r];
        }
        __syncthreads();
#pragma unroll
        for (int i = 0; i < 2; ++i) {
            const int slot = tid + i * 256;       // 0..511
            const float s = red[0][slot] + red[1][slot] +
                            red[2][slot] + red[3][slot];
            if (p == 0) {
                const int dd = slot >> 3, r = slot & 7;
                if (r < nr) kT[(size_t)dd * NROW + bs0 + r] = s;
            } else {
                const int dd = slot & 63, r = slot >> 6;
                if (r < nr) {
                    const int bs = bs0 + r;
                    if (p == 1) {
                        vbuf[(size_t)bs * DD + dd] = s;
                    } else {
                        const int b = bs / SS, ss = bs % SS;
                        if (ss >= TT - 1)
                            qbuf[((size_t)b * TT + (ss - (TT - 1))) * DD + dd] = s;
                    }
                }
            }
        }
        __syncthreads();
    }
}

// ---------------------------------------------------------------------------
// Kernel 2: attention per (b, w). Phase 1 logits now read kT coalesced:
// lane = t, kT[dd][b*SS + w + t] consecutive. bias[dd][t] also coalesced.
// ---------------------------------------------------------------------------
__global__ __launch_bounds__(256) void attn_kernel(
    const float* __restrict__ kT,     // [DD][NROW]
    const float* __restrict__ vbuf,   // [NROW][DD]
    const float* __restrict__ qbuf,   // [BB*TT][DD]
    const float* __restrict__ bias,   // [DD][TT]
    float* __restrict__ out)          // [BB*TT][DD]
{
    __shared__ float qs[DD];
    __shared__ float wei[TT];
    __shared__ float red[8];
    __shared__ float partial[4][DD];

    const int bw  = blockIdx.x;        // 0 .. B*T-1
    const int b   = bw >> 9;
    const int w   = bw & (TT - 1);
    const int tid = threadIdx.x;
    const int wave = tid >> 6;
    const int lane = tid & 63;

    if (tid < DD) qs[tid] = qbuf[(size_t)bw * DD + tid];
    __syncthreads();

    // ---- phase 1: logits, coalesced in t ----
    const float* kcol = kT + (size_t)b * SS + w;   // + dd*NROW + t
    float l[2];
#pragma unroll
    for (int j = 0; j < 2; ++j) {
        const int t = tid + j * 256;
        float a0 = 0.f, a1 = 0.f;
#pragma unroll 4
        for (int dd = 0; dd < DD; dd += 2) {
            const float q0 = qs[dd],     q1 = qs[dd + 1];
            const float k0 = kcol[(size_t)dd * NROW + t];
            const float k1 = kcol[(size_t)(dd + 1) * NROW + t];
            const float b0 = bias[dd * TT + t];
            const float b1 = bias[(dd + 1) * TT + t];
            a0 = fmaf(q0, k0 + b0, a0);
            a1 = fmaf(q1, k1 + b1, a1);
        }
        l[j] = a0 + a1;
    }

    // ---- block max ----
    float m = fmaxf(l[0], l[1]);
#pragma unroll
    for (int off = 32; off; off >>= 1)
        m = fmaxf(m, __shfl_down(m, off, 64));
    if (lane == 0) red[wave] = m;
    __syncthreads();
    m = fmaxf(fmaxf(red[0], red[1]), fmaxf(red[2], red[3]));

    // ---- exp + block sum ----
    const float e0 = __expf(l[0] - m);
    const float e1 = __expf(l[1] - m);
    wei[tid]       = e0;
    wei[tid + 256] = e1;
    float ssum = e0 + e1;
#pragma unroll
    for (int off = 32; off; off >>= 1)
        ssum += __shfl_down(ssum, off, 64);
    if (lane == 0) red[4 + wave] = ssum;
    __syncthreads();
    const float inv = 1.f / (red[4] + red[5] + red[6] + red[7]);

    // ---- phase 2: out[d] = sum_t wei[t] * v[b, w+t, d]  (coalesced) ----
    {
        const int dd = lane;
        float a = 0.f;
        const float* vbase = vbuf + ((size_t)(b * SS + w)) * DD + dd;
        const int t0 = wave * 128;
#pragma unroll 4
        for (int t = t0; t < t0 + 128; ++t)
            a = fmaf(wei[t], vbase[(size_t)t * DD], a);
        partial[wave][dd] = a;
    }
    __syncthreads();

    if (tid < DD) {
        const float o = (partial[0][tid] + partial[1][tid] +
                         partial[2][tid] + partial[3][tid]) * inv;
        out[(size_t)bw * DD + tid] = o;
    }
}

// ---------------------------------------------------------------------------
extern "C" void kernel_launch(void* const* d_in, const int* in_sizes, int n_in,
                              void* d_out, int out_size, void* d_ws, size_t ws_size,
                              hipStream_t stream) {
    const float* x    = (const float*)d_in[0];
    const float* Wk   = (const float*)d_in[1];
    const float* Wv   = (const float*)d_in[2];
    const float* Wq   = (const float*)d_in[3];
    const float* bias = (const float*)d_in[4];
    float* out = (float*)d_out;

    float* kT   = (float*)d_ws;                     // DD*NROW floats
    float* vbuf = kT + (size_t)DD * NROW;           // NROW*DD floats
    float* qbuf = vbuf + (size_t)NROW * DD;         // BB*TT*DD floats

    const int nblk = (NROW + RR - 1) / RR;          // 512
    proj_kernel<<<nblk, 256, 0, stream>>>(x, Wk, Wv, Wq, kT, vbuf, qbuf);
    attn_kernel<<<BB * TT, 256, 0, stream>>>(kT, vbuf, qbuf, bias, out);
}